// Round 6
// baseline (215.749 us; speedup 1.0000x reference)
//
#include <hip/hip_runtime.h>
#include <hip/hip_bf16.h>
#include <stdint.h>

#define M_DIM 4096
#define N_DIM 4096
#define K_DIM 2048

typedef __bf16 bf16x8 __attribute__((ext_vector_type(8)));
typedef float f32x4 __attribute__((ext_vector_type(4)));
typedef unsigned short u16x8 __attribute__((ext_vector_type(8)));

// ---------------- fp32 -> bf16 (RNE) ----------------
__device__ __forceinline__ unsigned short f32_to_bf16(float f) {
  union { float f; unsigned int u; } c; c.f = f;
  unsigned int u = c.u;
  unsigned int r = (u + 0x7FFFu + ((u >> 16) & 1u)) >> 16;
  return (unsigned short)r;
}

// ---------------- async global -> LDS, 16B per lane ----------------
__device__ __forceinline__ void gload_lds16(const unsigned short* g, unsigned short* l) {
  __builtin_amdgcn_global_load_lds(
      (const __attribute__((address_space(1))) unsigned int*)g,
      (__attribute__((address_space(3))) unsigned int*)l,
      16, 0, 0);
}

// ---------------- manual grid barrier (graph-capture-safe) ----------------
// R6 CHANGE vs R5: hipLaunchCooperativeKernel hung the container twice —
// cooperative launches allocate runtime sync state that graph capture/replay
// does not reproduce, so cg::grid.sync() spins forever. This is the same
// mechanism cooperative sync uses internally (fence -> agent-scope release
// add -> acquire spin), but on OUR workspace counter, launched as a plain
// kernel. Deadlock-free by construction: 128KB dynamic LDS forces 1
// block/CU and grid = 256 = CU count, so all blocks are co-resident.
// Counter is zeroed by a hipMemsetAsync in kernel_launch each iteration.
__device__ __forceinline__ void grid_sync(unsigned int* bar, unsigned int nblk) {
  __syncthreads();
  if (threadIdx.x == 0) {
    __threadfence();  // prior global writes visible device-wide (L2 wb)
    __hip_atomic_fetch_add(bar, 1u, __ATOMIC_RELEASE, __HIP_MEMORY_SCOPE_AGENT);
    while (__hip_atomic_load(bar, __ATOMIC_ACQUIRE, __HIP_MEMORY_SCOPE_AGENT) <
           nblk) {
      __builtin_amdgcn_s_sleep(8);
    }
    __threadfence();  // belt-and-braces acquire-side invalidation
  }
  __syncthreads();
}

// Stage one 256x64 A-tile + 256x64 B-tile (4 calls each; 512 lanes x 16B
// = 64 rows per call). xg/wg/lA/lB already carry the per-thread offset
// (row tid>>3, col (tid&7)*8  ->  LDS addr = base + tid*16B, the linear
// map global_load_lds requires).
__device__ __forceinline__ void stage_tile(
    const unsigned short* xg, const unsigned short* wg,
    unsigned short* lA, unsigned short* lB, int k0) {
#pragma unroll
  for (int c = 0; c < 4; ++c) {
    gload_lds16(xg + (size_t)(c * 64) * K_DIM + k0, lA + c * 64 * 64);
    gload_lds16(wg + (size_t)(c * 64) * K_DIM + k0, lB + c * 64 * 64);
  }
}

// One K=64 compute step on a staged tile pair — R0's verified inner loop,
// UNMODIFIED. Ledger of schedule-level attacks on this structure, all
// refuted on hardware:
//   R1  8-phase counted-vmcnt port      65.5us (-12%): barriers convoy
//   R3  sched_barrier-pinned interleave 71.0us (-21%): defeats compiler
//   R4  32x32x16 shape                  72.4us (-24%): +4.0 cy/ds_read
//       bank conflict (6.29M = exactly 4 x 1.57M reads)
// Plain source order + 16x16x32 is the local optimum for this structure.
__device__ __forceinline__ void compute_tile(
    const unsigned short* As, const unsigned short* Bs,
    int wr, int wc, int lr, int q, f32x4 acc[4][8]) {
#pragma unroll
  for (int ks = 0; ks < 2; ++ks) {
    // granule G = ks*4 + q; swizzled col = (G ^ (lr&7)) * 8
    const int swcol = ((ks * 4 + q) ^ (lr & 7)) * 8;
    bf16x8 af[4], bfr[8];
#pragma unroll
    for (int i = 0; i < 4; ++i)
      af[i]  = *(const bf16x8*)(As + (wr + i * 16 + lr) * 64 + swcol);
#pragma unroll
    for (int i = 0; i < 8; ++i)
      bfr[i] = *(const bf16x8*)(Bs + (wc + i * 16 + lr) * 64 + swcol);
#pragma unroll
    for (int mi = 0; mi < 4; ++mi)
#pragma unroll
      for (int ni = 0; ni < 8; ++ni)
        acc[mi][ni] = __builtin_amdgcn_mfma_f32_16x16x32_bf16(
            af[mi], bfr[ni], acc[mi][ni], 0, 0, 0);
  }
}

// ============ FUSED kernel: cvt -> grid_sync -> gemm+lse -> grid_sync -> mish
// Theory (R5/R6): gemm (58.6us) + cvt (~16us) + finalize (~1us) sum to ~76us
// of the 153.7us total — the other ~75us is inter-dispatch launch/gap
// overhead across 3 kernels. One launch collapses it.
__global__ void __launch_bounds__(512, 2) fused_kernel(
    const float* __restrict__ x,             // [M][K] fp32
    const float* __restrict__ w,             // [N][K] fp32
    const float* __restrict__ bias,          // [N]
    float* __restrict__ out,                 // [M]
    float* __restrict__ S,                   // [M] workspace partial sums
    unsigned short* __restrict__ xb,         // [M][K] bf16, swizzled granules
    unsigned short* __restrict__ wb,         // [N][K] bf16, swizzled granules
    unsigned int* __restrict__ bar) {        // [2] grid-barrier counters (pre-zeroed)
  extern __shared__ __align__(16) unsigned short lds[];

  const int tid = threadIdx.x;
  const int bid = blockIdx.y * 16 + blockIdx.x;

  // ---- Phase A: fp32->bf16 conversion with the XOR column-granule swizzle
  // (granule g of row r within each 64-col K-tile holds source granule
  // g ^ (r&7)) so phase B's forced-linear global_load_lds staging yields a
  // bank-conflict-free LDS tile. 2,097,152 granules / 256 blocks = 8192 per
  // block = 16 per thread. Block 0 also zeroes S.
  if (bid == 0) {
#pragma unroll
    for (int k = 0; k < 8; ++k)
      S[tid + k * 512] = 0.f;
  }
  const int nG = M_DIM * K_DIM / 8;  // granules per tensor
#pragma unroll 4
  for (int it = 0; it < 16; ++it) {
    int i = bid * 8192 + it * 512 + tid;
    const float* src;
    unsigned short* dst;
    int gid;
    if (i < nG) { src = x; dst = xb; gid = i; }
    else        { src = w; dst = wb; gid = i - nG; }

    const int row = gid >> 8;        // K/8 = 256 granules per row
    const int cg  = gid & 255;
    const int kt  = cg >> 3;
    const int g   = cg & 7;
    const int sg  = g ^ (row & 7);   // swizzled source granule

    const float4* s4 =
        (const float4*)(src + (size_t)row * K_DIM + kt * 64 + sg * 8);
    float4 f0 = s4[0], f1 = s4[1];
    u16x8 o;
    o[0] = f32_to_bf16(f0.x); o[1] = f32_to_bf16(f0.y);
    o[2] = f32_to_bf16(f0.z); o[3] = f32_to_bf16(f0.w);
    o[4] = f32_to_bf16(f1.x); o[5] = f32_to_bf16(f1.y);
    o[6] = f32_to_bf16(f1.z); o[7] = f32_to_bf16(f1.w);
    ((u16x8*)dst)[gid] = o;
  }

  grid_sync(&bar[0], 256);  // all conversions + S zeroing visible device-wide

  // ---- Phase B: fused GEMM -> bias -> clamp -> sum exp(v-10) per row.
  // 256x256 block tile, 8 waves, each wave 64x128 (4x8 frags of 16x16x32
  // bf16). Double-buffered LDS, ONE barrier per K-tile: DMA for tile kt+1
  // issues right after the barrier and stays in flight across the whole
  // compute(kt) phase, so the barrier's vmcnt(0) drain is ~free.
  {
    unsigned short* As0 = lds;                  // 256*64 shorts = 32 KB
    unsigned short* As1 = lds + 16384;
    unsigned short* Bs0 = lds + 32768;
    unsigned short* Bs1 = lds + 49152;

    const int bm0 = blockIdx.y * 256;
    const int bn0 = blockIdx.x * 256;

    const int wave = tid >> 6, lane = tid & 63;
    const int wr = (wave & 3) * 64;    // wave row offset (0..192)
    const int wc = (wave >> 2) * 128;  // wave col offset (0/128)
    const int lr = lane & 15;
    const int q  = lane >> 4;

    f32x4 acc[4][8];
    const f32x4 zero = {0.f, 0.f, 0.f, 0.f};
#pragma unroll
    for (int mi = 0; mi < 4; ++mi)
#pragma unroll
      for (int ni = 0; ni < 8; ++ni)
        acc[mi][ni] = zero;

    const int srow = tid >> 3;        // 0..63
    const int scol = (tid & 7) * 8;

    const unsigned short* xg = xb + (size_t)(bm0 + srow) * K_DIM + scol;
    const unsigned short* wg = wb + (size_t)(bn0 + srow) * K_DIM + scol;
    unsigned short* lA = lds + tid * 8;            // into As0 (+16384: As1)
    unsigned short* lB = lds + 32768 + tid * 8;    // into Bs0 (+16384: Bs1)

    stage_tile(xg, wg, lA, lB, 0);                 // prologue: tile 0 -> buf0

    for (int kt = 0; kt < 32; kt += 2) {
      __syncthreads();  // drains this wave's DMA (tile kt, issued a full
                        // compute-phase ago) + syncs: buf1 free to overwrite
      if (kt + 1 < 32)
        stage_tile(xg, wg, lA + 16384, lB + 16384, (kt + 1) * 64);
      compute_tile(As0, Bs0, wr, wc, lr, q, acc);

      __syncthreads();  // drains tile kt+1 DMA; buf0 free to overwrite
      if (kt + 2 < 32)
        stage_tile(xg, wg, lA, lB, (kt + 2) * 64);
      compute_tile(As1, Bs1, wr, wc, lr, q, acc);
    }

    // Epilogue: bias + clamp + exp(v-10); reduce across 16 lanes (128 cols);
    // one fire-and-forget atomic per row per wave (32 contributions/row).
    float bv[8];
#pragma unroll
    for (int ni = 0; ni < 8; ++ni)
      bv[ni] = bias[bn0 + wc + ni * 16 + lr];

#pragma unroll
    for (int mi = 0; mi < 4; ++mi) {
#pragma unroll
      for (int reg = 0; reg < 4; ++reg) {
        float s = 0.f;
#pragma unroll
        for (int ni = 0; ni < 8; ++ni) {
          float v = acc[mi][ni][reg] + bv[ni];  // SCALE_FACTOR*2 == 1.0
          v = fminf(fmaxf(v, -10.f), 10.f);
          s += __expf(v - 10.f);
        }
        s += __shfl_xor(s, 1);
        s += __shfl_xor(s, 2);
        s += __shfl_xor(s, 4);
        s += __shfl_xor(s, 8);
        if (lr == 0)
          atomicAdd(&S[bm0 + wr + mi * 16 + q * 4 + reg], s);
      }
    }
  }

  grid_sync(&bar[1], 256);  // all row partial sums visible device-wide

  // ---- Phase C: lse = 10 + log(S); mish(lse). 256 blocks x 16 rows. ----
  if (tid < 16) {
    int r = bid * 16 + tid;
    float lse = 10.0f + logf(S[r]);
    float sp = fmaxf(lse, 0.f) + log1pf(expf(-fabsf(lse)));  // stable softplus
    out[r] = lse * tanhf(sp);
  }
}

extern "C" void kernel_launch(void* const* d_in, const int* in_sizes, int n_in,
                              void* d_out, int out_size, void* d_ws, size_t ws_size,
                              hipStream_t stream) {
  const float* x = (const float*)d_in[0];   // [4096, 2048]
  const float* W = (const float*)d_in[1];   // [4096, 2048]
  const float* b = (const float*)d_in[2];   // [4096]
  float* out = (float*)d_out;               // [4096]

  char* ws = (char*)d_ws;
  float* S = (float*)ws;                                       // 16 KB
  unsigned short* xb = (unsigned short*)(ws + 16384);          // 16 MB
  unsigned short* wb = (unsigned short*)(ws + 16384 + (size_t)M_DIM * K_DIM * 2);
  unsigned int* bar = (unsigned int*)(ws + 16384 + 2 * (size_t)M_DIM * K_DIM * 2);

  // Barrier counters must be zero each iteration (workspace may be
  // re-poisoned between runs). hipMemsetAsync is graph-capture-safe and
  // replays with the graph.
  hipMemsetAsync(bar, 0, 64, stream);

  // 128 KB dynamic LDS needs the opt-in attribute (idempotent, capture-safe).
  hipFuncSetAttribute((const void*)fused_kernel,
                      hipFuncAttributeMaxDynamicSharedMemorySize, 131072);

  dim3 grid(N_DIM / 256, M_DIM / 256);  // 16 x 16 = 256 blocks = 1/CU exactly
  fused_kernel<<<grid, 512, 131072, stream>>>(x, W, b, out, S, xb, wb, bar);
}

// Round 7
// 162.190 us; speedup vs baseline: 1.3302x; 1.3302x over previous
//
#include <hip/hip_runtime.h>
#include <hip/hip_bf16.h>
#include <stdint.h>

#define M_DIM 4096
#define N_DIM 4096
#define K_DIM 2048

typedef __bf16 bf16x8 __attribute__((ext_vector_type(8)));
typedef float f32x4 __attribute__((ext_vector_type(4)));
typedef unsigned short u16x8 __attribute__((ext_vector_type(8)));

// ---------------- fp32 -> bf16 (RNE) ----------------
__device__ __forceinline__ unsigned short f32_to_bf16(float f) {
  union { float f; unsigned int u; } c; c.f = f;
  unsigned int u = c.u;
  unsigned int r = (u + 0x7FFFu + ((u >> 16) & 1u)) >> 16;
  return (unsigned short)r;
}

// Convert BOTH tensors fp32->bf16 with the XOR column-granule swizzle
// (granule g of row r within each 64-col K-tile holds source granule
// g ^ (r&7)) so the forced-linear global_load_lds staging yields a
// bank-conflict-free LDS tile. Block 0 additionally zeroes S.
// NOTE (R6 lesson): this stays a SEPARATE dispatch. Fusing it into the
// gemm kernel (which carries 128KB LDS -> 1 block/CU -> 2 waves/SIMD)
// starved it of TLP: ~1.4 TB/s instead of near-full BW, +~70us.
__global__ void __launch_bounds__(256) cvt_swz_kernel(
    const float* __restrict__ x, const float* __restrict__ w,
    unsigned short* __restrict__ xb, unsigned short* __restrict__ wb,
    float* __restrict__ S) {
  if (blockIdx.x == 0) {
#pragma unroll
    for (int k = 0; k < 16; ++k)
      S[threadIdx.x + k * 256] = 0.f;
  }

  const int nG = M_DIM * K_DIM / 8;  // granules per tensor
  int i = blockIdx.x * 256 + threadIdx.x;
  const float* src;
  unsigned short* dst;
  int gid;
  if (i < nG) { src = x; dst = xb; gid = i; }
  else        { src = w; dst = wb; gid = i - nG; }

  const int row = gid >> 8;        // K/8 = 256 granules per row
  const int cg  = gid & 255;
  const int kt  = cg >> 3;
  const int g   = cg & 7;
  const int sg  = g ^ (row & 7);   // swizzled source granule

  const float4* s4 = (const float4*)(src + (size_t)row * K_DIM + kt * 64 + sg * 8);
  float4 f0 = s4[0], f1 = s4[1];
  u16x8 o;
  o[0] = f32_to_bf16(f0.x); o[1] = f32_to_bf16(f0.y);
  o[2] = f32_to_bf16(f0.z); o[3] = f32_to_bf16(f0.w);
  o[4] = f32_to_bf16(f1.x); o[5] = f32_to_bf16(f1.y);
  o[6] = f32_to_bf16(f1.z); o[7] = f32_to_bf16(f1.w);
  ((u16x8*)dst)[gid] = o;
}

// ---------------- async global -> LDS, 16B per lane ----------------
__device__ __forceinline__ void gload_lds16(const unsigned short* g, unsigned short* l) {
  __builtin_amdgcn_global_load_lds(
      (const __attribute__((address_space(1))) unsigned int*)g,
      (__attribute__((address_space(3))) unsigned int*)l,
      16, 0, 0);
}

// Stage one 256x64 A-tile + 256x64 B-tile (4 calls each; 512 lanes x 16B
// = 64 rows per call). xg/wg/lA/lB already carry the per-thread offset
// (row tid>>3, col (tid&7)*8  ->  LDS addr = base + tid*16B, the linear
// map global_load_lds requires).
__device__ __forceinline__ void stage_tile(
    const unsigned short* xg, const unsigned short* wg,
    unsigned short* lA, unsigned short* lB, int k0) {
#pragma unroll
  for (int c = 0; c < 4; ++c) {
    gload_lds16(xg + (size_t)(c * 64) * K_DIM + k0, lA + c * 64 * 64);
    gload_lds16(wg + (size_t)(c * 64) * K_DIM + k0, lB + c * 64 * 64);
  }
}

// One K=64 compute step on a staged tile pair — R0's verified inner loop,
// UNMODIFIED. Ledger of attacks on this structure, all refuted on HW:
//   R1  8-phase counted-vmcnt port      65.5us (-12%): barriers convoy
//   R3  sched_barrier-pinned interleave 71.0us (-21%): defeats compiler
//   R4  32x32x16 shape                  72.4us (-24%): +4.0 cy/ds_read
//       bank conflict (6.29M = exactly 4 x 1.57M reads)
//   R6  fused-single-kernel             regression came from cvt phase,
//       gemm phase itself unchanged
// Plain source order + 16x16x32 at 1173 TF is this structure's optimum.
__device__ __forceinline__ void compute_tile(
    const unsigned short* As, const unsigned short* Bs,
    int wr, int wc, int lr, int q, f32x4 acc[4][8]) {
#pragma unroll
  for (int ks = 0; ks < 2; ++ks) {
    // granule G = ks*4 + q; swizzled col = (G ^ (lr&7)) * 8
    const int swcol = ((ks * 4 + q) ^ (lr & 7)) * 8;
    bf16x8 af[4], bfr[8];
#pragma unroll
    for (int i = 0; i < 4; ++i)
      af[i]  = *(const bf16x8*)(As + (wr + i * 16 + lr) * 64 + swcol);
#pragma unroll
    for (int i = 0; i < 8; ++i)
      bfr[i] = *(const bf16x8*)(Bs + (wc + i * 16 + lr) * 64 + swcol);
#pragma unroll
    for (int mi = 0; mi < 4; ++mi)
#pragma unroll
      for (int ni = 0; ni < 8; ++ni)
        acc[mi][ni] = __builtin_amdgcn_mfma_f32_16x16x32_bf16(
            af[mi], bfr[ni], acc[mi][ni], 0, 0, 0);
  }
}

// ---------------- fused GEMM -> clamp -> sum exp(v-10) -> (last block) mish
// 256x256 block tile, 512 threads = 8 waves, each wave 64x128 (4x8 frags of
// 16x16x32 bf16). DOUBLE-BUFFERED LDS (128 KB dynamic), ONE barrier per
// K-tile. R7 CHANGE: the finalize kernel is folded in via a last-block
// ticket — after the epilogue atomics, each block increments a device-scope
// ticket; the block that sees old==255 knows every S contribution is
// globally visible (acq_rel RMW; each block's atomics drained by the
// pre-ticket __syncthreads) and computes mish(10+log(S)) for all 4096 rows.
// Saves one dispatch + launch gap (~6-8us of the measured ~6us/launch).
__global__ void __launch_bounds__(512, 2) gemm_lse_kernel(
    const unsigned short* __restrict__ xb,   // [M][K] bf16, swizzled granules
    const unsigned short* __restrict__ wb,   // [N][K] bf16, swizzled granules
    const float* __restrict__ bias,          // [N]
    float* __restrict__ S,                   // [M] partial sums of exp(clamp(v)-10)
    float* __restrict__ out,                 // [M] final mish(lse)
    unsigned int* __restrict__ ticket) {     // [1] pre-zeroed each iteration
  extern __shared__ __align__(16) unsigned short lds[];
  unsigned short* As0 = lds;                  // 256*64 shorts = 32 KB
  unsigned short* As1 = lds + 16384;
  unsigned short* Bs0 = lds + 32768;
  unsigned short* Bs1 = lds + 49152;

  const int tid = threadIdx.x;
  const int bm0 = blockIdx.y * 256;
  const int bn0 = blockIdx.x * 256;

  const int wave = tid >> 6, lane = tid & 63;
  const int wr = (wave & 3) * 64;    // wave row offset (0..192)
  const int wc = (wave >> 2) * 128;  // wave col offset (0/128)
  const int lr = lane & 15;
  const int q  = lane >> 4;

  f32x4 acc[4][8];
  const f32x4 zero = {0.f, 0.f, 0.f, 0.f};
#pragma unroll
  for (int mi = 0; mi < 4; ++mi)
#pragma unroll
    for (int ni = 0; ni < 8; ++ni)
      acc[mi][ni] = zero;

  const int srow = tid >> 3;        // 0..63
  const int scol = (tid & 7) * 8;

  const unsigned short* xg = xb + (size_t)(bm0 + srow) * K_DIM + scol;
  const unsigned short* wg = wb + (size_t)(bn0 + srow) * K_DIM + scol;
  unsigned short* lA = lds + tid * 8;            // into As0 (+16384 for As1)
  unsigned short* lB = lds + 32768 + tid * 8;    // into Bs0 (+16384 for Bs1)

  stage_tile(xg, wg, lA, lB, 0);                 // prologue: tile 0 -> buf0

  for (int kt = 0; kt < 32; kt += 2) {
    __syncthreads();  // drains this wave's DMA (tile kt, issued a full
                      // compute-phase ago) + syncs: buf1 free to overwrite
    if (kt + 1 < 32)
      stage_tile(xg, wg, lA + 16384, lB + 16384, (kt + 1) * 64);
    compute_tile(As0, Bs0, wr, wc, lr, q, acc);

    __syncthreads();  // drains tile kt+1 DMA; buf0 free to overwrite
    if (kt + 2 < 32)
      stage_tile(xg, wg, lA, lB, (kt + 2) * 64);
    compute_tile(As1, Bs1, wr, wc, lr, q, acc);
  }

  // Epilogue: bias + clamp + exp(v-10); reduce across 16 lanes (128 cols);
  // one fire-and-forget atomic per row per wave (32 contributions/row total).
  float bv[8];
#pragma unroll
  for (int ni = 0; ni < 8; ++ni)
    bv[ni] = bias[bn0 + wc + ni * 16 + lr];

#pragma unroll
  for (int mi = 0; mi < 4; ++mi) {
#pragma unroll
    for (int reg = 0; reg < 4; ++reg) {
      float s = 0.f;
#pragma unroll
      for (int ni = 0; ni < 8; ++ni) {
        float v = acc[mi][ni][reg] + bv[ni];  // SCALE_FACTOR*2 == 1.0
        v = fminf(fmaxf(v, -10.f), 10.f);
        s += __expf(v - 10.f);
      }
      s += __shfl_xor(s, 1);
      s += __shfl_xor(s, 2);
      s += __shfl_xor(s, 4);
      s += __shfl_xor(s, 8);
      if (lr == 0)
        atomicAdd(&S[bm0 + wr + mi * 16 + q * 4 + reg], s);
    }
  }

  // ---- last-block finalize ----
  volatile int* flag = (volatile int*)lds;  // LDS dead after main loop
  __syncthreads();  // all waves' S atomics issued + drained (barrier implies
                    // vmcnt(0)); LDS safe to reuse
  if (tid == 0) {
    unsigned int old = __hip_atomic_fetch_add(ticket, 1u, __ATOMIC_ACQ_REL,
                                              __HIP_MEMORY_SCOPE_AGENT);
    *flag = (old == 255) ? 1 : 0;
  }
  __syncthreads();
  if (*flag) {
    // Every block's release-increment preceded our acquire-read of 255, and
    // S-adds are device-scope RMWs at the L2 coherence point -> all visible.
#pragma unroll
    for (int it = 0; it < 8; ++it) {
      int r = it * 512 + tid;
      float lse = 10.0f + logf(S[r]);
      float sp = fmaxf(lse, 0.f) + log1pf(expf(-fabsf(lse)));  // stable softplus
      out[r] = lse * tanhf(sp);
    }
  }
}

extern "C" void kernel_launch(void* const* d_in, const int* in_sizes, int n_in,
                              void* d_out, int out_size, void* d_ws, size_t ws_size,
                              hipStream_t stream) {
  const float* x = (const float*)d_in[0];   // [4096, 2048]
  const float* W = (const float*)d_in[1];   // [4096, 2048]
  const float* b = (const float*)d_in[2];   // [4096]
  float* out = (float*)d_out;               // [4096]

  char* ws = (char*)d_ws;
  float* S = (float*)ws;                                       // 16 KB
  unsigned short* xb = (unsigned short*)(ws + 16384);          // 16 MB
  unsigned short* wb = (unsigned short*)(ws + 16384 + (size_t)M_DIM * K_DIM * 2);
  unsigned int* ticket =
      (unsigned int*)(ws + 16384 + 2 * (size_t)M_DIM * K_DIM * 2);

  // Ticket must be zero each iteration (workspace may be re-poisoned).
  // hipMemsetAsync is graph-capture-safe and replays with the graph (R6).
  hipMemsetAsync(ticket, 0, 64, stream);

  const int nG2 = 2 * M_DIM * K_DIM / 8;  // both tensors, 16B granules
  cvt_swz_kernel<<<nG2 / 256, 256, 0, stream>>>(x, W, xb, wb, S);

  // 128 KB dynamic LDS needs the opt-in attribute (idempotent, capture-safe).
  hipFuncSetAttribute((const void*)gemm_lse_kernel,
                      hipFuncAttributeMaxDynamicSharedMemorySize, 131072);
  dim3 grid(N_DIM / 256, M_DIM / 256);  // 16 x 16 = 256 blocks, 1/CU
  gemm_lse_kernel<<<grid, 512, 131072, stream>>>(xb, wb, b, S, out, ticket);
}

// Round 8
// 154.547 us; speedup vs baseline: 1.3960x; 1.0494x over previous
//
#include <hip/hip_runtime.h>
#include <hip/hip_bf16.h>
#include <stdint.h>

#define M_DIM 4096
#define N_DIM 4096
#define K_DIM 2048

typedef __bf16 bf16x8 __attribute__((ext_vector_type(8)));
typedef float f32x4 __attribute__((ext_vector_type(4)));
typedef unsigned short u16x8 __attribute__((ext_vector_type(8)));

// ---------------- fp32 -> bf16 (RNE) ----------------
__device__ __forceinline__ unsigned short f32_to_bf16(float f) {
  union { float f; unsigned int u; } c; c.f = f;
  unsigned int u = c.u;
  unsigned int r = (u + 0x7FFFu + ((u >> 16) & 1u)) >> 16;
  return (unsigned short)r;
}

// Convert BOTH tensors fp32->bf16 with the XOR column-granule swizzle
// (granule g of row r within each 64-col K-tile holds source granule
// g ^ (r&7)) so the forced-linear global_load_lds staging yields a
// bank-conflict-free LDS tile. Block 0 additionally zeroes S.
// R6 lesson: stays a SEPARATE dispatch (fusing into the 128KB-LDS gemm
// kernel starved it of TLP: ~1.4 TB/s, +70us).
__global__ void __launch_bounds__(256) cvt_swz_kernel(
    const float* __restrict__ x, const float* __restrict__ w,
    unsigned short* __restrict__ xb, unsigned short* __restrict__ wb,
    float* __restrict__ S) {
  if (blockIdx.x == 0) {
#pragma unroll
    for (int k = 0; k < 16; ++k)
      S[threadIdx.x + k * 256] = 0.f;
  }

  const int nG = M_DIM * K_DIM / 8;  // granules per tensor
  int i = blockIdx.x * 256 + threadIdx.x;
  const float* src;
  unsigned short* dst;
  int gid;
  if (i < nG) { src = x; dst = xb; gid = i; }
  else        { src = w; dst = wb; gid = i - nG; }

  const int row = gid >> 8;        // K/8 = 256 granules per row
  const int cg  = gid & 255;
  const int kt  = cg >> 3;
  const int g   = cg & 7;
  const int sg  = g ^ (row & 7);   // swizzled source granule

  const float4* s4 = (const float4*)(src + (size_t)row * K_DIM + kt * 64 + sg * 8);
  float4 f0 = s4[0], f1 = s4[1];
  u16x8 o;
  o[0] = f32_to_bf16(f0.x); o[1] = f32_to_bf16(f0.y);
  o[2] = f32_to_bf16(f0.z); o[3] = f32_to_bf16(f0.w);
  o[4] = f32_to_bf16(f1.x); o[5] = f32_to_bf16(f1.y);
  o[6] = f32_to_bf16(f1.z); o[7] = f32_to_bf16(f1.w);
  ((u16x8*)dst)[gid] = o;
}

// ---------------- async global -> LDS, 16B per lane ----------------
__device__ __forceinline__ void gload_lds16(const unsigned short* g, unsigned short* l) {
  __builtin_amdgcn_global_load_lds(
      (const __attribute__((address_space(1))) unsigned int*)g,
      (__attribute__((address_space(3))) unsigned int*)l,
      16, 0, 0);
}

// Stage one 256x64 A-tile + 256x64 B-tile (4 calls each; 512 lanes x 16B
// = 64 rows per call). xg/wg/lA/lB already carry the per-thread offset
// (row tid>>3, col (tid&7)*8  ->  LDS addr = base + tid*16B, the linear
// map global_load_lds requires).
__device__ __forceinline__ void stage_tile(
    const unsigned short* xg, const unsigned short* wg,
    unsigned short* lA, unsigned short* lB, int k0) {
#pragma unroll
  for (int c = 0; c < 4; ++c) {
    gload_lds16(xg + (size_t)(c * 64) * K_DIM + k0, lA + c * 64 * 64);
    gload_lds16(wg + (size_t)(c * 64) * K_DIM + k0, lB + c * 64 * 64);
  }
}

// One K=64 compute step on a staged tile pair — R0's verified MFMA order,
// with R8's ONE change: the per-lane LDS byte-offsets (aoff/boff, constant
// across all 32 K-tiles) are hoisted out of the loop; reads become
// base + compile-time immediate, folded into ds_read offset: fields.
// Rationale: R0's VALUBusy 22.7% = ~1087 cy/tile = ~270 VALU instr/wave/
// tile (~8 per memory op) — the compiler recomputed every swizzled address
// each tile because the buffer base alternates. Those VALU ops sit in the
// wave's serial issue stream between barrier and MFMAs.
// Ledger of refuted attacks on this structure (all HW-measured):
//   R1 8-phase counted-vmcnt  65.5us  | R3 pinned interleave  71.0us
//   R4 32x32x16 shape         72.4us  | R6 mega-fusion: cvt starved
//   R7 ticket-finalize       +8.5us total
__device__ __forceinline__ void compute_tile(
    const char* Ab, const char* Bb,   // byte pointers to this tile's buffers
    const int aoff[2], const int boff[2], f32x4 acc[4][8]) {
#pragma unroll
  for (int ks = 0; ks < 2; ++ks) {
    const char* pa = Ab + aoff[ks];
    const char* pb = Bb + boff[ks];
    bf16x8 af[4], bfr[8];
#pragma unroll
    for (int i = 0; i < 4; ++i)
      af[i]  = *(const bf16x8*)(pa + i * 2048);
#pragma unroll
    for (int i = 0; i < 8; ++i)
      bfr[i] = *(const bf16x8*)(pb + i * 2048);
#pragma unroll
    for (int mi = 0; mi < 4; ++mi)
#pragma unroll
      for (int ni = 0; ni < 8; ++ni)
        acc[mi][ni] = __builtin_amdgcn_mfma_f32_16x16x32_bf16(
            af[mi], bfr[ni], acc[mi][ni], 0, 0, 0);
  }
}

// ---------------- fused GEMM -> clamp -> sum exp(v-10) per row ----------------
// 256x256 block tile, 512 threads = 8 waves, each wave 64x128 (4x8 frags of
// 16x16x32 bf16). DOUBLE-BUFFERED LDS (128 KB dynamic), ONE barrier per
// K-tile: DMA for tile kt+1 issues right after the barrier and stays in
// flight across the whole compute(kt) phase, so the barrier's vmcnt(0)
// drain is ~free.
__global__ void __launch_bounds__(512, 2) gemm_lse_kernel(
    const unsigned short* __restrict__ xb,   // [M][K] bf16, swizzled granules
    const unsigned short* __restrict__ wb,   // [N][K] bf16, swizzled granules
    const float* __restrict__ bias,          // [N]
    float* __restrict__ S) {                 // [M] partial sums of exp(clamp(v)-10)
  extern __shared__ __align__(16) unsigned short lds[];
  const char* ldsb = (const char*)lds;
  // A buffers at bytes 0 / 32768; B buffers at 65536 / 98304.

  const int tid = threadIdx.x;
  const int bm0 = blockIdx.y * 256;
  const int bn0 = blockIdx.x * 256;

  const int wave = tid >> 6, lane = tid & 63;
  const int wr = (wave & 3) * 64;    // wave row offset (0..192)
  const int wc = (wave >> 2) * 128;  // wave col offset (0/128)
  const int lr = lane & 15;
  const int q  = lane >> 4;

  // Tile-invariant per-lane LDS byte offsets (row*128 + swizzled granule*16).
  int aoff[2], boff[2];
#pragma unroll
  for (int ks = 0; ks < 2; ++ks) {
    const int swb = (((ks * 4 + q) ^ (lr & 7)) * 16);
    aoff[ks] = (wr + lr) * 128 + swb;
    boff[ks] = (wc + lr) * 128 + swb;
  }

  f32x4 acc[4][8];
  const f32x4 zero = {0.f, 0.f, 0.f, 0.f};
#pragma unroll
  for (int mi = 0; mi < 4; ++mi)
#pragma unroll
    for (int ni = 0; ni < 8; ++ni)
      acc[mi][ni] = zero;

  const int srow = tid >> 3;        // 0..63
  const int scol = (tid & 7) * 8;

  const unsigned short* xg = xb + (size_t)(bm0 + srow) * K_DIM + scol;
  const unsigned short* wg = wb + (size_t)(bn0 + srow) * K_DIM + scol;
  unsigned short* lA = lds + tid * 8;            // into As0 (+16384 for As1)
  unsigned short* lB = lds + 32768 + tid * 8;    // into Bs0 (+16384 for Bs1)

  stage_tile(xg, wg, lA, lB, 0);                 // prologue: tile 0 -> buf0

  for (int kt = 0; kt < 32; kt += 2) {
    __syncthreads();  // drains this wave's DMA (tile kt, issued a full
                      // compute-phase ago) + syncs: buf1 free to overwrite
    if (kt + 1 < 32)
      stage_tile(xg, wg, lA + 16384, lB + 16384, (kt + 1) * 64);
    compute_tile(ldsb, ldsb + 65536, aoff, boff, acc);

    __syncthreads();  // drains tile kt+1 DMA; buf0 free to overwrite
    if (kt + 2 < 32)
      stage_tile(xg, wg, lA, lB, (kt + 2) * 64);
    compute_tile(ldsb + 32768, ldsb + 98304, aoff, boff, acc);
  }

  // Epilogue: bias + clamp + exp(v-10); reduce across 16 lanes (128 cols);
  // one fire-and-forget atomic per row per wave (32 contributions/row total).
  float bv[8];
#pragma unroll
  for (int ni = 0; ni < 8; ++ni)
    bv[ni] = bias[bn0 + wc + ni * 16 + lr];

#pragma unroll
  for (int mi = 0; mi < 4; ++mi) {
#pragma unroll
    for (int reg = 0; reg < 4; ++reg) {
      float s = 0.f;
#pragma unroll
      for (int ni = 0; ni < 8; ++ni) {
        float v = acc[mi][ni][reg] + bv[ni];  // SCALE_FACTOR*2 == 1.0
        v = fminf(fmaxf(v, -10.f), 10.f);
        s += __expf(v - 10.f);
      }
      s += __shfl_xor(s, 1);
      s += __shfl_xor(s, 2);
      s += __shfl_xor(s, 4);
      s += __shfl_xor(s, 8);
      if (lr == 0)
        atomicAdd(&S[bm0 + wr + mi * 16 + q * 4 + reg], s);
    }
  }
}

// ---------------- finalize: lse = 10 + log(S); mish(lse) ----------------
__global__ void __launch_bounds__(256) finalize_kernel(const float* __restrict__ S,
                                                       float* __restrict__ out) {
  int i = blockIdx.x * blockDim.x + threadIdx.x;
  float lse = 10.0f + logf(S[i]);
  float sp = fmaxf(lse, 0.f) + log1pf(expf(-fabsf(lse)));  // stable softplus
  out[i] = lse * tanhf(sp);
}

extern "C" void kernel_launch(void* const* d_in, const int* in_sizes, int n_in,
                              void* d_out, int out_size, void* d_ws, size_t ws_size,
                              hipStream_t stream) {
  const float* x = (const float*)d_in[0];   // [4096, 2048]
  const float* W = (const float*)d_in[1];   // [4096, 2048]
  const float* b = (const float*)d_in[2];   // [4096]
  float* out = (float*)d_out;               // [4096]

  char* ws = (char*)d_ws;
  float* S = (float*)ws;                                       // 16 KB
  unsigned short* xb = (unsigned short*)(ws + 16384);          // 16 MB
  unsigned short* wb = (unsigned short*)(ws + 16384 + (size_t)M_DIM * K_DIM * 2);

  const int nG2 = 2 * M_DIM * K_DIM / 8;  // both tensors, 16B granules
  cvt_swz_kernel<<<nG2 / 256, 256, 0, stream>>>(x, W, xb, wb, S);

  // 128 KB dynamic LDS needs the opt-in attribute (idempotent, capture-safe).
  hipFuncSetAttribute((const void*)gemm_lse_kernel,
                      hipFuncAttributeMaxDynamicSharedMemorySize, 131072);
  dim3 grid(N_DIM / 256, M_DIM / 256);  // 16 x 16 = 256 blocks, 1/CU
  gemm_lse_kernel<<<grid, 512, 131072, stream>>>(xb, wb, b, S);

  finalize_kernel<<<M_DIM / 256, 256, 0, stream>>>(S, out);
}